// Round 2
// baseline (272.725 us; speedup 1.0000x reference)
//
#include <hip/hip_runtime.h>
#include <hip/hip_bf16.h>
#include <hip/hip_cooperative_groups.h>

namespace cg = cooperative_groups;

#define H 256
#define L2H 512
#define MAXLEN 256
#define NLAYERS 4
#define VOCAB 50257

// d_out layout: logp[50257], hidden_new[4*256], attn_weights[256]  (dtype = flag)
#define OUT_LOGP 0
#define OUT_HID  50257
#define OUT_ATTN 51281

// ws layout (fp32 elements) — 2305 floats = 9220 B
#define WS_SCORE  0       // 256 attn scores
#define WS_SM     256     // 256 softmax'd attn weights
#define WS_APP    512     // 256 attn_applied accumulator
#define WS_X0     768     // 256
#define WS_X1     1024    // 256
#define WS_PM     1280    // 512 per-block running max
#define WS_PS     1792    // 512 per-block running sum
#define WS_FLAG   2304    // 1.0f => inputs are bf16 ; 0.0f => inputs are fp32

// k_logits geometry: 512 blocks x 4 waves x 2 half-waves = 4096 concurrent rows
#define LOGITS_BLOCKS 512
#define LOGITS_STRIDE 4096

// fused pre-logits kernel geometry: 64 blocks x 4 waves = 256 waves (1 per row)
#define FUSED_BLOCKS 64

typedef unsigned short u16;

__device__ __forceinline__ float bf2f(u16 u) {
    return __uint_as_float(((unsigned int)u) << 16);
}

__device__ __forceinline__ u16 f2bf(float f) {
    unsigned int x = __float_as_uint(f);
    unsigned int r = x + 0x7fff + ((x >> 16) & 1);
    return (u16)(r >> 16);
}

// ---- dtype-polymorphic load/store helpers ----
template<bool BF16>
__device__ __forceinline__ float ld1(const void* p, size_t i) {
    if (BF16) return bf2f(((const u16*)p)[i]);
    else      return ((const float*)p)[i];
}

template<bool BF16>
__device__ __forceinline__ float4 ld4(const void* p, size_t i) {
    if (BF16) {
        ushort4 w = *(const ushort4*)((const u16*)p + i);
        return make_float4(bf2f(w.x), bf2f(w.y), bf2f(w.z), bf2f(w.w));
    } else {
        return *(const float4*)((const float*)p + i);
    }
}

template<bool BF16>
__device__ __forceinline__ void ld8(const void* p, size_t i, float* f) {
    if (BF16) {
        uint4 u = *(const uint4*)((const u16*)p + i);
        f[0] = bf2f(u.x & 0xffff); f[1] = bf2f(u.x >> 16);
        f[2] = bf2f(u.y & 0xffff); f[3] = bf2f(u.y >> 16);
        f[4] = bf2f(u.z & 0xffff); f[5] = bf2f(u.z >> 16);
        f[6] = bf2f(u.w & 0xffff); f[7] = bf2f(u.w >> 16);
    } else {
        const float4* q = (const float4*)((const float*)p + i);
        float4 a = q[0], b = q[1];
        f[0] = a.x; f[1] = a.y; f[2] = a.z; f[3] = a.w;
        f[4] = b.x; f[5] = b.y; f[6] = b.z; f[7] = b.w;
    }
}

template<bool BF16>
__device__ __forceinline__ void st(void* p, size_t i, float v) {
    if (BF16) ((u16*)p)[i] = f2bf(v);
    else      ((float*)p)[i] = v;
}

// ---------------- K0: sniff dtype of float inputs ----------------
__global__ __launch_bounds__(64) void k_sniff(const void* emb, float* ws) {
    int lane = threadIdx.x;
    float b = fabsf(bf2f(((const u16*)emb)[lane]));
    #pragma unroll
    for (int off = 32; off; off >>= 1) b = fmaxf(b, __shfl_xor(b, off));
    if (lane == 0) ws[WS_FLAG] = (b < 1.0f) ? 1.0f : 0.0f;
}

// ---------------- Fused pre-logits chain (cooperative) ----------------
// 64 blocks x 256 threads = 256 waves; wave wv owns output row wv in every
// GEMV phase. 7 grid.sync()s replace 8 kernel launches (x2 dtype variants).
// Phases: attn_score -> softmax -> attn_apply -> comb -> gru x4.
template<bool BF16>
__global__ __launch_bounds__(256) void k_fused_pre(
    const int* __restrict__ tok, const void* __restrict__ emb,
    const void* __restrict__ hidden,
    const void* __restrict__ attn_w, const void* __restrict__ attn_b,
    const void* __restrict__ enc,
    const void* __restrict__ comb_w, const void* __restrict__ comb_b,
    const void* __restrict__ gwih, const void* __restrict__ gwhh,
    const void* __restrict__ gbih, const void* __restrict__ gbhh,
    float* __restrict__ ws, void* __restrict__ out)
{
    // uniform gate: either every block syncs, or every block returns here
    if ((ws[WS_FLAG] > 0.5f) != BF16) return;
    cg::grid_group grid = cg::this_grid();

    const int tid  = threadIdx.x;
    const int lane = tid & 63;
    const int wv   = (blockIdx.x << 2) | (tid >> 6);   // 0..255: row owned by this wave
    const int j8   = lane * 8;
    const size_t es = BF16 ? 2 : 4;

    __shared__ float red[256];

    // ---- Phase 1: attn scores = concat(emb, h0) @ attn_w.T + attn_b ----
    {
        float xin[8];
        if (lane < 32) ld8<BF16>(emb, (size_t)tok[0] * H + j8, xin);
        else           ld8<BF16>(hidden, (size_t)(j8 - H), xin);   // hidden[0]
        float wf[8]; ld8<BF16>(attn_w, (size_t)wv * L2H + j8, wf);
        float v = 0.f;
        #pragma unroll
        for (int q = 0; q < 8; ++q) v += xin[q] * wf[q];
        #pragma unroll
        for (int off = 32; off; off >>= 1) v += __shfl_xor(v, off);
        if (lane == 0) ws[WS_SCORE + wv] = v + ld1<BF16>(attn_b, wv);
    }
    grid.sync();

    // ---- Phase 2: softmax over 256 scores (block 0); zero attn_applied ----
    if (blockIdx.x == 0) {
        float s = ws[WS_SCORE + tid];
        red[tid] = s; __syncthreads();
        for (int off = 128; off; off >>= 1) {
            if (tid < off) red[tid] = fmaxf(red[tid], red[tid + off]);
            __syncthreads();
        }
        float M = red[0]; __syncthreads();
        float e = __expf(s - M);
        red[tid] = e; __syncthreads();
        for (int off = 128; off; off >>= 1) {
            if (tid < off) red[tid] += red[tid + off];
            __syncthreads();
        }
        float w = e / red[0];
        ws[WS_SM + tid] = w;
        ws[WS_APP + tid] = 0.f;
        st<BF16>(out, OUT_ATTN + tid, w);
    }
    grid.sync();

    // ---- Phase 3: attn_applied = attn_weights @ encoder_outputs (blocks 0..15) ----
    if (blockIdx.x < 16) {
        int l0 = blockIdx.x * 16;
        float acc = 0.f;
        for (int l = l0; l < l0 + 16; ++l)
            acc += ws[WS_SM + l] * ld1<BF16>(enc, (size_t)l * H + tid);
        atomicAdd(&ws[WS_APP + tid], acc);
    }
    grid.sync();

    // ---- Phase 4: x = relu(concat(emb, attn_applied) @ comb_w.T + comb_b) ----
    {
        float xin[8];
        if (lane < 32) {
            ld8<BF16>(emb, (size_t)tok[0] * H + j8, xin);
        } else {
            const float4* p = (const float4*)(ws + WS_APP + (j8 - H));
            float4 a = p[0], b = p[1];
            xin[0] = a.x; xin[1] = a.y; xin[2] = a.z; xin[3] = a.w;
            xin[4] = b.x; xin[5] = b.y; xin[6] = b.z; xin[7] = b.w;
        }
        float wf[8]; ld8<BF16>(comb_w, (size_t)wv * L2H + j8, wf);
        float v = 0.f;
        #pragma unroll
        for (int q = 0; q < 8; ++q) v += xin[q] * wf[q];
        #pragma unroll
        for (int off = 32; off; off >>= 1) v += __shfl_xor(v, off);
        if (lane == 0) ws[WS_X0 + wv] = fmaxf(v + ld1<BF16>(comb_b, wv), 0.f);
    }
    grid.sync();

    // ---- Phases 5..8: 4 GRU layers (PyTorch gate order r,z,n), wave per row ----
    const int e4 = lane * 4;
    for (int l = 0; l < NLAYERS; ++l) {
        const float* xin_p = ws + ((l & 1) ? WS_X1 : WS_X0);
        float*       xout  = ws + ((l & 1) ? WS_X0 : WS_X1);
        const char* wih = (const char*)gwih + (size_t)l * 3 * H * H * es;
        const char* whh = (const char*)gwhh + (size_t)l * 3 * H * H * es;
        const char* bih = (const char*)gbih + (size_t)l * 3 * H * es;
        const char* bhh = (const char*)gbhh + (size_t)l * 3 * H * es;
        const char* hprev = (const char*)hidden + (size_t)l * H * es;
        char*       hout  = (char*)out + (size_t)(OUT_HID + l * H) * es;

        float4 xv = *(const float4*)(xin_p + e4);
        float4 hv = ld4<BF16>(hprev, e4);
        const int i = wv;

        float4 wri = ld4<BF16>(wih, (size_t)(i        ) * H + e4);
        float4 wzi = ld4<BF16>(wih, (size_t)(H + i    ) * H + e4);
        float4 wni = ld4<BF16>(wih, (size_t)(2 * H + i) * H + e4);
        float4 wrh = ld4<BF16>(whh, (size_t)(i        ) * H + e4);
        float4 wzh = ld4<BF16>(whh, (size_t)(H + i    ) * H + e4);
        float4 wnh = ld4<BF16>(whh, (size_t)(2 * H + i) * H + e4);

        float a = wri.x * xv.x + wri.y * xv.y + wri.z * xv.z + wri.w * xv.w
                + wrh.x * hv.x + wrh.y * hv.y + wrh.z * hv.z + wrh.w * hv.w;
        float b = wzi.x * xv.x + wzi.y * xv.y + wzi.z * xv.z + wzi.w * xv.w
                + wzh.x * hv.x + wzh.y * hv.y + wzh.z * hv.z + wzh.w * hv.w;
        float c = wni.x * xv.x + wni.y * xv.y + wni.z * xv.z + wni.w * xv.w;
        float d = wnh.x * hv.x + wnh.y * hv.y + wnh.z * hv.z + wnh.w * hv.w;

        #pragma unroll
        for (int off = 32; off; off >>= 1) {
            a += __shfl_xor(a, off);
            b += __shfl_xor(b, off);
            c += __shfl_xor(c, off);
            d += __shfl_xor(d, off);
        }
        if (lane == 0) {
            float r = 1.f / (1.f + __expf(-(a + ld1<BF16>(bih, i) + ld1<BF16>(bhh, i))));
            float z = 1.f / (1.f + __expf(-(b + ld1<BF16>(bih, H + i) + ld1<BF16>(bhh, H + i))));
            float n = tanhf(c + ld1<BF16>(bih, 2 * H + i) + r * (d + ld1<BF16>(bhh, 2 * H + i)));
            float hold = ld1<BF16>(hprev, i);
            float hn = (1.f - z) * n + z * hold;
            xout[i] = hn;
            st<BF16>(hout, i, hn);
        }
        if (l < NLAYERS - 1) grid.sync();
    }
    // final x is in ws[WS_X0]; k_logits follows in stream order
}

// ---------------- K6: logits GEMV + per-block online softmax partials ----------------
// 512 blocks x 256 thr = 2048 waves; each wave is two 32-lane row-groups
// (16B/lane spans a full bf16 row); 4 rows in flight per thread.
template<bool BF16>
__global__ __launch_bounds__(256) void k_logits(
    const void* __restrict__ out_w, const void* __restrict__ out_b,
    const float* __restrict__ xin, float* __restrict__ ws,
    void* __restrict__ out)
{
    if ((ws[WS_FLAG] > 0.5f) != BF16) return;
    int tid  = threadIdx.x;
    int wv   = (blockIdx.x << 2) | (tid >> 6);   // global wave id, 0..2047
    int lane = tid & 63;
    int l32  = lane & 31;
    int half = lane >> 5;

    // x fragment: 8 consecutive elements per lane (row-group covers 32*8=256)
    float xf[8];
    {
        const float4* xp = (const float4*)(xin + l32 * 8);
        float4 a = xp[0], b = xp[1];
        xf[0] = a.x; xf[1] = a.y; xf[2] = a.z; xf[3] = a.w;
        xf[4] = b.x; xf[5] = b.y; xf[6] = b.z; xf[7] = b.w;
    }

    float m = -1e30f, s = 0.f;
    const int r0 = wv * 2 + half;                 // 0..4095
    for (int r = r0; r < VOCAB; r += 4 * LOGITS_STRIDE) {
        int r1 = r + LOGITS_STRIDE;
        int r2 = r + 2 * LOGITS_STRIDE;
        int r3 = r + 3 * LOGITS_STRIDE;
        bool h1 = r1 < VOCAB, h2 = r2 < VOCAB, h3 = r3 < VOCAB;

        // issue all independent loads first (4 x 16B weight + 4 bias scalars)
        float w0[8], w1[8], w2[8], w3[8];
        float b0 = 0.f, b1 = 0.f, b2 = 0.f, b3 = 0.f;
        ld8<BF16>(out_w, (size_t)r * H + l32 * 8, w0);
        b0 = ld1<BF16>(out_b, r);
        if (h1) { ld8<BF16>(out_w, (size_t)r1 * H + l32 * 8, w1); b1 = ld1<BF16>(out_b, r1); }
        if (h2) { ld8<BF16>(out_w, (size_t)r2 * H + l32 * 8, w2); b2 = ld1<BF16>(out_b, r2); }
        if (h3) { ld8<BF16>(out_w, (size_t)r3 * H + l32 * 8, w3); b3 = ld1<BF16>(out_b, r3); }

        float v0 = w0[0]*xf[0]+w0[1]*xf[1]+w0[2]*xf[2]+w0[3]*xf[3]
                 + w0[4]*xf[4]+w0[5]*xf[5]+w0[6]*xf[6]+w0[7]*xf[7];
        float v1 = h1 ? (w1[0]*xf[0]+w1[1]*xf[1]+w1[2]*xf[2]+w1[3]*xf[3]
                       + w1[4]*xf[4]+w1[5]*xf[5]+w1[6]*xf[6]+w1[7]*xf[7]) : 0.f;
        float v2 = h2 ? (w2[0]*xf[0]+w2[1]*xf[1]+w2[2]*xf[2]+w2[3]*xf[3]
                       + w2[4]*xf[4]+w2[5]*xf[5]+w2[6]*xf[6]+w2[7]*xf[7]) : 0.f;
        float v3 = h3 ? (w3[0]*xf[0]+w3[1]*xf[1]+w3[2]*xf[2]+w3[3]*xf[3]
                       + w3[4]*xf[4]+w3[5]*xf[5]+w3[6]*xf[6]+w3[7]*xf[7]) : 0.f;

        // interleaved 32-lane butterfly (xor<32 stays within each half-wave)
        #pragma unroll
        for (int off = 16; off; off >>= 1) {
            v0 += __shfl_xor(v0, off);
            v1 += __shfl_xor(v1, off);
            v2 += __shfl_xor(v2, off);
            v3 += __shfl_xor(v3, off);
        }
        v0 += b0; v1 += b1; v2 += b2; v3 += b3;

        if (l32 == 0) {
            st<BF16>(out, OUT_LOGP + r, v0);
            if (h1) st<BF16>(out, OUT_LOGP + r1, v1);
            if (h2) st<BF16>(out, OUT_LOGP + r2, v2);
            if (h3) st<BF16>(out, OUT_LOGP + r3, v3);
        }

        { float mn = fmaxf(m, v0); s = s * __expf(m - mn) + __expf(v0 - mn); m = mn; }
        if (h1) { float mn = fmaxf(m, v1); s = s * __expf(m - mn) + __expf(v1 - mn); m = mn; }
        if (h2) { float mn = fmaxf(m, v2); s = s * __expf(m - mn) + __expf(v2 - mn); m = mn; }
        if (h3) { float mn = fmaxf(m, v3); s = s * __expf(m - mn) + __expf(v3 - mn); m = mn; }
    }

    // merge the two half-waves (all lanes in a half hold identical m,s)
    {
        float mo = __shfl_xor(m, 32), so = __shfl_xor(s, 32);
        float M = fmaxf(m, mo);
        s = s * __expf(m - M) + so * __expf(mo - M);
        m = M;
    }

    // block-level merge of 4 waves -> one partial per block (512 total)
    __shared__ float bm[4], bs[4];
    if (lane == 0) { bm[tid >> 6] = m; bs[tid >> 6] = s; }
    __syncthreads();
    if (tid == 0) {
        float M01 = fmaxf(bm[0], bm[1]);
        float S01 = bs[0] * __expf(bm[0] - M01) + bs[1] * __expf(bm[1] - M01);
        float M23 = fmaxf(bm[2], bm[3]);
        float S23 = bs[2] * __expf(bm[2] - M23) + bs[3] * __expf(bm[3] - M23);
        float Mx = fmaxf(M01, M23);
        float S  = S01 * __expf(M01 - Mx) + S23 * __expf(M23 - Mx);
        ws[WS_PM + blockIdx.x] = Mx;
        ws[WS_PS + blockIdx.x] = S;
    }
}

// ---------------- K7: combine partials (redundant per block) + rewrite logp ----------------
template<bool BF16>
__global__ __launch_bounds__(256) void k_logsoftmax(
    const float* __restrict__ ws, void* __restrict__ out)
{
    if ((ws[WS_FLAG] > 0.5f) != BF16) return;
    __shared__ float sm[256], ss[256];
    int t = threadIdx.x;
    float m1 = ws[WS_PM + t],       s1 = ws[WS_PS + t];
    float m2 = ws[WS_PM + 256 + t], s2 = ws[WS_PS + 256 + t];
    float M = fmaxf(m1, m2);
    float S = s1 * __expf(m1 - M) + s2 * __expf(m2 - M);
    sm[t] = M; ss[t] = S; __syncthreads();
    for (int off = 128; off; off >>= 1) {
        if (t < off) {
            float ma = sm[t], mb = sm[t + off];
            float Mx = fmaxf(ma, mb);
            ss[t] = ss[t] * __expf(ma - Mx) + ss[t + off] * __expf(mb - Mx);
            sm[t] = Mx;
        }
        __syncthreads();
    }
    float c = sm[0] + __logf(ss[0]);
    for (int r = blockIdx.x * blockDim.x + t; r < VOCAB; r += gridDim.x * blockDim.x) {
        float v = BF16 ? bf2f(((const u16*)out)[OUT_LOGP + r])
                       : ((const float*)out)[OUT_LOGP + r];
        st<BF16>(out, OUT_LOGP + r, v - c);
    }
}

template<bool BF16>
static void run_pipeline(const int* tok, void* const* d_in, float* ws, void* out,
                         hipStream_t stream) {
    // locals with exact kernel-parameter types for cooperative-launch marshaling
    const int*  a_tok    = tok;
    const void* a_emb    = d_in[3];
    const void* a_hidden = d_in[1];
    const void* a_attn_w = d_in[4];
    const void* a_attn_b = d_in[5];
    const void* a_enc    = d_in[2];
    const void* a_comb_w = d_in[6];
    const void* a_comb_b = d_in[7];
    const void* a_gwih   = d_in[8];
    const void* a_gwhh   = d_in[9];
    const void* a_gbih   = d_in[10];
    const void* a_gbhh   = d_in[11];
    float*      a_ws     = ws;
    void*       a_out    = out;

    void* args[14] = {
        (void*)&a_tok, (void*)&a_emb, (void*)&a_hidden,
        (void*)&a_attn_w, (void*)&a_attn_b, (void*)&a_enc,
        (void*)&a_comb_w, (void*)&a_comb_b,
        (void*)&a_gwih, (void*)&a_gwhh, (void*)&a_gbih, (void*)&a_gbhh,
        (void*)&a_ws, (void*)&a_out
    };
    hipLaunchCooperativeKernel((void*)k_fused_pre<BF16>,
                               dim3(FUSED_BLOCKS), dim3(256), args, 0, stream);

    const void* out_w = d_in[12];
    const void* out_b = d_in[13];
    k_logits<BF16><<<dim3(LOGITS_BLOCKS), dim3(256), 0, stream>>>(out_w, out_b, ws + WS_X0, ws, out);
    k_logsoftmax<BF16><<<dim3(128), dim3(256), 0, stream>>>(ws, out);
}

extern "C" void kernel_launch(void* const* d_in, const int* in_sizes, int n_in,
                              void* d_out, int out_size, void* d_ws, size_t ws_size,
                              hipStream_t stream) {
    const int* tok = (const int*)d_in[0];
    float* ws = (float*)d_ws;

    k_sniff<<<dim3(1), dim3(64), 0, stream>>>(d_in[3], ws);
    run_pipeline<true>(tok, d_in, ws, d_out, stream);   // bf16 variant (self-gated)
    run_pipeline<false>(tok, d_in, ws, d_out, stream);  // fp32 variant (self-gated)
}

// Round 3
// 207.659 us; speedup vs baseline: 1.3133x; 1.3133x over previous
//
#include <hip/hip_runtime.h>
#include <hip/hip_bf16.h>

#define H 256
#define L2H 512
#define NLAYERS 4
#define VOCAB 50257

// d_out layout: logp[50257], hidden_new[4*256], attn_weights[256]  (dtype = flag)
#define OUT_LOGP 0
#define OUT_HID  50257
#define OUT_ATTN 51281

// ws layout (fp32 elements) — stays within 2305 floats
#define WS_SCORE  0       // 256 attn scores
#define WS_BARS   256     // 16 uint barrier slots (reuses old WS_SM region)
#define WS_APP    512     // 256 attn_applied accumulator (zeroed by k_init)
#define WS_X0     768     // 256
#define WS_X1     1024    // 256
#define WS_PM     1280    // 64 per-block running max (rest unused)
#define WS_PS     1792    // 64 per-block running sum (rest unused)
#define WS_FLAG   2304    // 1.0f => inputs are bf16 ; 0.0f => fp32

#define NBLK 64           // fused kernel blocks; << 256 CUs => co-resident

typedef unsigned short u16;

__device__ __forceinline__ float bf2f(u16 u) {
    return __uint_as_float(((unsigned int)u) << 16);
}

__device__ __forceinline__ u16 f2bf(float f) {
    unsigned int x = __float_as_uint(f);
    unsigned int r = x + 0x7fff + ((x >> 16) & 1);
    return (u16)(r >> 16);
}

// ---- dtype-polymorphic load/store helpers ----
template<bool BF16>
__device__ __forceinline__ float ld1(const void* p, size_t i) {
    if (BF16) return bf2f(((const u16*)p)[i]);
    else      return ((const float*)p)[i];
}

template<bool BF16>
__device__ __forceinline__ float4 ld4(const void* p, size_t i) {
    if (BF16) {
        ushort4 w = *(const ushort4*)((const u16*)p + i);
        return make_float4(bf2f(w.x), bf2f(w.y), bf2f(w.z), bf2f(w.w));
    } else {
        return *(const float4*)((const float*)p + i);
    }
}

template<bool BF16>
__device__ __forceinline__ void ld8(const void* p, size_t i, float* f) {
    if (BF16) {
        uint4 u = *(const uint4*)((const u16*)p + i);
        f[0] = bf2f(u.x & 0xffff); f[1] = bf2f(u.x >> 16);
        f[2] = bf2f(u.y & 0xffff); f[3] = bf2f(u.y >> 16);
        f[4] = bf2f(u.z & 0xffff); f[5] = bf2f(u.z >> 16);
        f[6] = bf2f(u.w & 0xffff); f[7] = bf2f(u.w >> 16);
    } else {
        const float4* q = (const float4*)((const float*)p + i);
        float4 a = q[0], b = q[1];
        f[0] = a.x; f[1] = a.y; f[2] = a.z; f[3] = a.w;
        f[4] = b.x; f[5] = b.y; f[6] = b.z; f[7] = b.w;
    }
}

template<bool BF16>
__device__ __forceinline__ void st(void* p, size_t i, float v) {
    if (BF16) ((u16*)p)[i] = f2bf(v);
    else      ((float*)p)[i] = v;
}

// ---- lightweight device-scope grid barrier ----
// Requires all NBLK blocks co-resident (64 blocks of 256 thr on 256 CUs).
// Slots zeroed by k_init each iteration. __threadfence() at device scope
// emits the L2-writeback/L1-inv cache ops needed for cross-XCD visibility.
__device__ __forceinline__ void gbar(unsigned* bars, int i) {
    __syncthreads();                      // all block's stores drained (vmcnt 0)
    if (threadIdx.x == 0) {
        __threadfence();                  // release
        __hip_atomic_fetch_add(&bars[i], 1u, __ATOMIC_RELAXED, __HIP_MEMORY_SCOPE_AGENT);
        while (__hip_atomic_load(&bars[i], __ATOMIC_RELAXED, __HIP_MEMORY_SCOPE_AGENT) < (unsigned)NBLK)
            __builtin_amdgcn_s_sleep(1);
        __threadfence();                  // acquire
    }
    __syncthreads();
}

// ---------------- K0: init barriers + WS_APP, sniff dtype ----------------
__global__ __launch_bounds__(256) void k_init(const void* emb, float* ws) {
    int tid = threadIdx.x;
    if (tid < 16) ((unsigned*)(ws + WS_BARS))[tid] = 0u;
    ws[WS_APP + tid] = 0.f;
    if (tid < 64) {
        float b = fabsf(bf2f(((const u16*)emb)[tid]));
        #pragma unroll
        for (int off = 32; off; off >>= 1) b = fmaxf(b, __shfl_xor(b, off));
        if (tid == 0) ws[WS_FLAG] = (b < 1.0f) ? 1.0f : 0.0f;
    }
}

// ---------------- The whole network in one kernel ----------------
// 64 blocks x 256 threads. Wave wv = blockIdx*4+wid owns row wv in each GEMV
// phase. 8 custom barriers sequence: score | softmax+apply | comb | gru x4 |
// logits | combine+rewrite.
template<bool BF16>
__device__ __forceinline__ void pipeline(
    const int* __restrict__ tok, const void* __restrict__ emb,
    const void* __restrict__ hidden,
    const void* __restrict__ attn_w, const void* __restrict__ attn_b,
    const void* __restrict__ enc,
    const void* __restrict__ comb_w, const void* __restrict__ comb_b,
    const void* __restrict__ gwih, const void* __restrict__ gwhh,
    const void* __restrict__ gbih, const void* __restrict__ gbhh,
    const void* __restrict__ out_w, const void* __restrict__ out_b,
    float* __restrict__ ws, void* __restrict__ out)
{
    unsigned* bars = (unsigned*)(ws + WS_BARS);
    const int tid  = threadIdx.x;
    const int lane = tid & 63;
    const int wid  = tid >> 6;
    const int wv   = (blockIdx.x << 2) | wid;   // 0..255
    const int j8   = lane * 8;
    const size_t es = BF16 ? 2 : 4;

    __shared__ float lds[256];
    __shared__ float wsm[256];

    // ---- P0: attn scores = concat(emb, h0) @ attn_w.T + attn_b ----
    {
        float xin[8];
        if (lane < 32) ld8<BF16>(emb, (size_t)tok[0] * H + j8, xin);
        else           ld8<BF16>(hidden, (size_t)(j8 - H), xin);   // hidden[0]
        float wf[8]; ld8<BF16>(attn_w, (size_t)wv * L2H + j8, wf);
        float v = 0.f;
        #pragma unroll
        for (int q = 0; q < 8; ++q) v += xin[q] * wf[q];
        #pragma unroll
        for (int off = 32; off; off >>= 1) v += __shfl_xor(v, off);
        if (lane == 0) ws[WS_SCORE + wv] = v + ld1<BF16>(attn_b, wv);
    }
    gbar(bars, 0);

    // ---- P1: softmax over 256 scores (redundant per block) + apply slices ----
    {
        float s = ws[WS_SCORE + tid];
        lds[tid] = s; __syncthreads();
        for (int off = 128; off; off >>= 1) {
            if (tid < off) lds[tid] = fmaxf(lds[tid], lds[tid + off]);
            __syncthreads();
        }
        float M = lds[0]; __syncthreads();
        float e = __expf(s - M);
        lds[tid] = e; __syncthreads();
        for (int off = 128; off; off >>= 1) {
            if (tid < off) lds[tid] += lds[tid + off];
            __syncthreads();
        }
        float w = e / lds[0];
        wsm[tid] = w; __syncthreads();
        if (blockIdx.x == 0) st<BF16>(out, OUT_ATTN + tid, w);
        // apply: blocks 0..15, 16 l-rows each, coalesced row reads + atomics
        if (blockIdx.x < 16) {
            int l0 = blockIdx.x * 16;
            float acc = 0.f;
            #pragma unroll
            for (int k = 0; k < 16; ++k)
                acc += wsm[l0 + k] * ld1<BF16>(enc, (size_t)(l0 + k) * H + tid);
            atomicAdd(&ws[WS_APP + tid], acc);
        }
    }
    gbar(bars, 1);

    // ---- P2: x = relu(concat(emb, attn_applied) @ comb_w.T + comb_b) ----
    {
        float xin[8];
        if (lane < 32) {
            ld8<BF16>(emb, (size_t)tok[0] * H + j8, xin);
        } else {
            const float4* p = (const float4*)(ws + WS_APP + (j8 - H));
            float4 a = p[0], b = p[1];
            xin[0] = a.x; xin[1] = a.y; xin[2] = a.z; xin[3] = a.w;
            xin[4] = b.x; xin[5] = b.y; xin[6] = b.z; xin[7] = b.w;
        }
        float wf[8]; ld8<BF16>(comb_w, (size_t)wv * L2H + j8, wf);
        float v = 0.f;
        #pragma unroll
        for (int q = 0; q < 8; ++q) v += xin[q] * wf[q];
        #pragma unroll
        for (int off = 32; off; off >>= 1) v += __shfl_xor(v, off);
        if (lane == 0) ws[WS_X0 + wv] = fmaxf(v + ld1<BF16>(comb_b, wv), 0.f);
    }
    gbar(bars, 2);

    // ---- P3..P6: 4 GRU layers (PyTorch gate order r,z,n), wave per row ----
    const int e4 = lane * 4;
    for (int l = 0; l < NLAYERS; ++l) {
        const float* xin_p = ws + ((l & 1) ? WS_X1 : WS_X0);
        float*       xout  = ws + ((l & 1) ? WS_X0 : WS_X1);
        const char* wih = (const char*)gwih + (size_t)l * 3 * H * H * es;
        const char* whh = (const char*)gwhh + (size_t)l * 3 * H * H * es;
        const char* bih = (const char*)gbih + (size_t)l * 3 * H * es;
        const char* bhh = (const char*)gbhh + (size_t)l * 3 * H * es;
        const char* hprev = (const char*)hidden + (size_t)l * H * es;
        char*       hout  = (char*)out + (size_t)(OUT_HID + l * H) * es;

        float4 xv = *(const float4*)(xin_p + e4);
        float4 hv = ld4<BF16>(hprev, e4);
        const int i = wv;

        float4 wri = ld4<BF16>(wih, (size_t)(i        ) * H + e4);
        float4 wzi = ld4<BF16>(wih, (size_t)(H + i    ) * H + e4);
        float4 wni = ld4<BF16>(wih, (size_t)(2 * H + i) * H + e4);
        float4 wrh = ld4<BF16>(whh, (size_t)(i        ) * H + e4);
        float4 wzh = ld4<BF16>(whh, (size_t)(H + i    ) * H + e4);
        float4 wnh = ld4<BF16>(whh, (size_t)(2 * H + i) * H + e4);

        float a = wri.x * xv.x + wri.y * xv.y + wri.z * xv.z + wri.w * xv.w
                + wrh.x * hv.x + wrh.y * hv.y + wrh.z * hv.z + wrh.w * hv.w;
        float b = wzi.x * xv.x + wzi.y * xv.y + wzi.z * xv.z + wzi.w * xv.w
                + wzh.x * hv.x + wzh.y * hv.y + wzh.z * hv.z + wzh.w * hv.w;
        float c = wni.x * xv.x + wni.y * xv.y + wni.z * xv.z + wni.w * xv.w;
        float d = wnh.x * hv.x + wnh.y * hv.y + wnh.z * hv.z + wnh.w * hv.w;

        #pragma unroll
        for (int off = 32; off; off >>= 1) {
            a += __shfl_xor(a, off);
            b += __shfl_xor(b, off);
            c += __shfl_xor(c, off);
            d += __shfl_xor(d, off);
        }
        if (lane == 0) {
            float r = 1.f / (1.f + __expf(-(a + ld1<BF16>(bih, i) + ld1<BF16>(bhh, i))));
            float z = 1.f / (1.f + __expf(-(b + ld1<BF16>(bih, H + i) + ld1<BF16>(bhh, H + i))));
            float n = tanhf(c + ld1<BF16>(bih, 2 * H + i) + r * (d + ld1<BF16>(bhh, 2 * H + i)));
            float hold = ld1<BF16>(hprev, i);
            float hn = (1.f - z) * n + z * hold;
            xout[i] = hn;
            st<BF16>(hout, i, hn);
        }
        gbar(bars, 3 + l);   // bar 3,4,5,6 (bar 6 doubles as pre-logits sync)
    }

    // ---- P7: logits GEMV + online-softmax partials ----
    // 512 row-groups (8 per block, 32 lanes each); 8 rows in flight per thread
    // => 64 blk * 256 thr * 8 rows * 16 B = 2 MB in flight (Little's law OK).
    {
        const int grp = (blockIdx.x << 3) | (tid >> 5);  // 0..511
        const int l32 = tid & 31;

        float xf[8];
        {
            const float4* xp = (const float4*)(ws + WS_X0 + l32 * 8);
            float4 a = xp[0], b = xp[1];
            xf[0] = a.x; xf[1] = a.y; xf[2] = a.z; xf[3] = a.w;
            xf[4] = b.x; xf[5] = b.y; xf[6] = b.z; xf[7] = b.w;
        }

        float m = -1e30f, s = 0.f;
        for (int base = 0; base < VOCAB; base += 8 * 512) {
            float wf[8][8]; float bb[8]; float v[8]; bool ok[8];
            #pragma unroll
            for (int k = 0; k < 8; ++k) {
                int r = base + k * 512 + grp;
                ok[k] = (r < VOCAB);
                if (ok[k]) {
                    ld8<BF16>(out_w, (size_t)r * H + l32 * 8, wf[k]);
                    bb[k] = ld1<BF16>(out_b, r);
                } else {
                    #pragma unroll
                    for (int q = 0; q < 8; ++q) wf[k][q] = 0.f;
                    bb[k] = 0.f;
                }
            }
            #pragma unroll
            for (int k = 0; k < 8; ++k) {
                v[k] = wf[k][0]*xf[0] + wf[k][1]*xf[1] + wf[k][2]*xf[2] + wf[k][3]*xf[3]
                     + wf[k][4]*xf[4] + wf[k][5]*xf[5] + wf[k][6]*xf[6] + wf[k][7]*xf[7];
            }
            #pragma unroll
            for (int off = 16; off; off >>= 1) {
                #pragma unroll
                for (int k = 0; k < 8; ++k) v[k] += __shfl_xor(v[k], off);
            }
            #pragma unroll
            for (int k = 0; k < 8; ++k) {
                if (ok[k]) {
                    int r = base + k * 512 + grp;
                    float vv = v[k] + bb[k];
                    if (l32 == 0) st<BF16>(out, OUT_LOGP + r, vv);
                    float mn = fmaxf(m, vv);
                    s = s * __expf(m - mn) + __expf(vv - mn);
                    m = mn;
                }
            }
        }

        // merge the two 32-lane halves of each wave
        {
            float mo = __shfl_xor(m, 32), so = __shfl_xor(s, 32);
            float M = fmaxf(m, mo);
            s = s * __expf(m - M) + so * __expf(mo - M);
            m = M;
        }
        // block merge: 4 waves -> 1 partial per block
        if (lane == 0) { lds[wid] = m; lds[4 + wid] = s; }
        __syncthreads();
        if (tid == 0) {
            float M01 = fmaxf(lds[0], lds[1]);
            float S01 = lds[4] * __expf(lds[0] - M01) + lds[5] * __expf(lds[1] - M01);
            float M23 = fmaxf(lds[2], lds[3]);
            float S23 = lds[6] * __expf(lds[2] - M23) + lds[7] * __expf(lds[3] - M23);
            float Mx = fmaxf(M01, M23);
            float S  = S01 * __expf(M01 - Mx) + S23 * __expf(M23 - Mx);
            ws[WS_PM + blockIdx.x] = Mx;
            ws[WS_PS + blockIdx.x] = S;
        }
    }
    gbar(bars, 7);

    // ---- P8: combine 64 partials (redundant per block) + rewrite logp ----
    {
        if (tid < 64) {
            float m = ws[WS_PM + tid], s = ws[WS_PS + tid];
            #pragma unroll
            for (int off = 32; off; off >>= 1) {
                float mo = __shfl_xor(m, off), so = __shfl_xor(s, off);
                float M = fmaxf(m, mo);
                s = s * __expf(m - M) + so * __expf(mo - M);
                m = M;
            }
            if (tid == 0) lds[0] = m + __logf(s);
        }
        __syncthreads();
        float c = lds[0];
        for (int r = (blockIdx.x << 8) + tid; r < VOCAB; r += NBLK * 256) {
            float v = BF16 ? bf2f(((const u16*)out)[OUT_LOGP + r])
                           : ((const float*)out)[OUT_LOGP + r];
            st<BF16>(out, OUT_LOGP + r, v - c);
        }
    }
}

__global__ __launch_bounds__(256, 1) void k_all(
    const int* __restrict__ tok, const void* __restrict__ emb,
    const void* __restrict__ hidden,
    const void* __restrict__ attn_w, const void* __restrict__ attn_b,
    const void* __restrict__ enc,
    const void* __restrict__ comb_w, const void* __restrict__ comb_b,
    const void* __restrict__ gwih, const void* __restrict__ gwhh,
    const void* __restrict__ gbih, const void* __restrict__ gbhh,
    const void* __restrict__ out_w, const void* __restrict__ out_b,
    float* __restrict__ ws, void* __restrict__ out)
{
    if (ws[WS_FLAG] > 0.5f)
        pipeline<true >(tok, emb, hidden, attn_w, attn_b, enc, comb_w, comb_b,
                        gwih, gwhh, gbih, gbhh, out_w, out_b, ws, out);
    else
        pipeline<false>(tok, emb, hidden, attn_w, attn_b, enc, comb_w, comb_b,
                        gwih, gwhh, gbih, gbhh, out_w, out_b, ws, out);
}

extern "C" void kernel_launch(void* const* d_in, const int* in_sizes, int n_in,
                              void* d_out, int out_size, void* d_ws, size_t ws_size,
                              hipStream_t stream) {
    const int* tok = (const int*)d_in[0];
    float* ws = (float*)d_ws;

    k_init<<<dim3(1), dim3(256), 0, stream>>>(d_in[3], ws);
    k_all<<<dim3(NBLK), dim3(256), 0, stream>>>(
        tok, d_in[3], d_in[1], d_in[4], d_in[5], d_in[2], d_in[6], d_in[7],
        d_in[8], d_in[9], d_in[10], d_in[11], d_in[12], d_in[13],
        ws, d_out);
}

// Round 4
// 170.418 us; speedup vs baseline: 1.6003x; 1.2185x over previous
//
#include <hip/hip_runtime.h>
#include <hip/hip_bf16.h>

#define H 256
#define L2H 512
#define NLAYERS 4
#define VOCAB 50257

// d_out layout: logp[50257], hidden_new[4*256], attn_weights[256]  (dtype = flag)
#define OUT_LOGP 0
#define OUT_HID  50257
#define OUT_ATTN 51281

// ws layout (fp32 elements) — stays within 2305 floats
#define WS_SCORE  0       // 256 attn scores (coherent)
#define WS_BARS   256     // 256 uints: 16 groups x 16 slots (8 barriers used), 64B-strided groups
#define WS_APP    512     // 256 attn_applied accumulator (atomicAdd; zeroed by k_init)
#define WS_X0     768     // 256 (coherent)
#define WS_X1     1024    // 256 (coherent)
#define WS_PM     1280    // 256 per-block running max (coherent)
#define WS_PS     1792    // 256 per-block running sum (coherent)
#define WS_FLAG   2304    // 1.0f => inputs are bf16 ; 0.0f => fp32

#define NBLK 256          // 1 block/CU; co-resident (1024 waves << 8192 capacity)
#define NGRP 16           // barrier counter groups

typedef unsigned short u16;

__device__ __forceinline__ float bf2f(u16 u) {
    return __uint_as_float(((unsigned int)u) << 16);
}

__device__ __forceinline__ u16 f2bf(float f) {
    unsigned int x = __float_as_uint(f);
    unsigned int r = x + 0x7fff + ((x >> 16) & 1);
    return (u16)(r >> 16);
}

// ---- dtype-polymorphic load/store helpers (plain, cached) ----
template<bool BF16>
__device__ __forceinline__ float ld1(const void* p, size_t i) {
    if (BF16) return bf2f(((const u16*)p)[i]);
    else      return ((const float*)p)[i];
}

template<bool BF16>
__device__ __forceinline__ float4 ld4(const void* p, size_t i) {
    if (BF16) {
        ushort4 w = *(const ushort4*)((const u16*)p + i);
        return make_float4(bf2f(w.x), bf2f(w.y), bf2f(w.z), bf2f(w.w));
    } else {
        return *(const float4*)((const float*)p + i);
    }
}

template<bool BF16>
__device__ __forceinline__ void ld8(const void* p, size_t i, float* f) {
    if (BF16) {
        uint4 u = *(const uint4*)((const u16*)p + i);
        f[0] = bf2f(u.x & 0xffff); f[1] = bf2f(u.x >> 16);
        f[2] = bf2f(u.y & 0xffff); f[3] = bf2f(u.y >> 16);
        f[4] = bf2f(u.z & 0xffff); f[5] = bf2f(u.z >> 16);
        f[6] = bf2f(u.w & 0xffff); f[7] = bf2f(u.w >> 16);
    } else {
        const float4* q = (const float4*)((const float*)p + i);
        float4 a = q[0], b = q[1];
        f[0] = a.x; f[1] = a.y; f[2] = a.z; f[3] = a.w;
        f[4] = b.x; f[5] = b.y; f[6] = b.z; f[7] = b.w;
    }
}

template<bool BF16>
__device__ __forceinline__ void st(void* p, size_t i, float v) {
    if (BF16) ((u16*)p)[i] = f2bf(v);
    else      ((float*)p)[i] = v;
}

// ---- coherent (LLC, cache-bypassing) scalar access for cross-block data ----
__device__ __forceinline__ float ldc(const float* p) {
    return __hip_atomic_load(const_cast<float*>(p), __ATOMIC_RELAXED, __HIP_MEMORY_SCOPE_AGENT);
}
__device__ __forceinline__ void stc(float* p, float v) {
    __hip_atomic_store(p, v, __ATOMIC_RELAXED, __HIP_MEMORY_SCOPE_AGENT);
}

// ---- fence-free grid barrier ----
// All cross-block data moves via agent-scope (LLC) accesses, so no cache
// maintenance is needed. __syncthreads() drains vmcnt(0) => all this block's
// coherent stores are complete at the LLC before the arrive-add. 16 counters
// (64 B apart) kill same-address RMW serialization; lanes 0..15 each spin on
// one counter (single wide poll load).
__device__ __forceinline__ void gbar(unsigned* bars, int i, bool arrive, unsigned exp) {
    __syncthreads();
    if (arrive && threadIdx.x == 0)
        __hip_atomic_fetch_add(&bars[(blockIdx.x & (NGRP - 1)) * 16 + i], 1u,
                               __ATOMIC_RELAXED, __HIP_MEMORY_SCOPE_AGENT);
    if (threadIdx.x < NGRP) {
        while (__hip_atomic_load(&bars[threadIdx.x * 16 + i],
                                 __ATOMIC_RELAXED, __HIP_MEMORY_SCOPE_AGENT) < exp)
            __builtin_amdgcn_s_sleep(1);
    }
    __syncthreads();
}

// ---------------- K0: zero barriers + WS_APP, sniff dtype ----------------
__global__ __launch_bounds__(256) void k_init(const void* emb, float* ws) {
    int tid = threadIdx.x;
    ((unsigned*)(ws + WS_BARS))[tid] = 0u;
    ws[WS_APP + tid] = 0.f;
    if (tid < 64) {
        float b = fabsf(bf2f(((const u16*)emb)[tid]));
        #pragma unroll
        for (int off = 32; off; off >>= 1) b = fmaxf(b, __shfl_xor(b, off));
        if (tid == 0) ws[WS_FLAG] = (b < 1.0f) ? 1.0f : 0.0f;
    }
}

// ---------------- The whole network in one kernel ----------------
// Blocks 0..63: pre-logits chain (wave wv = bx*4+wid owns row wv), barriers
// 0..6 among themselves (exp 4/group). Blocks 64..255 wait at barrier 6.
// All 256 blocks: logits (8 x 32-lane row-groups each, ILP 8) -> barrier 7
// (exp 16/group) -> combine partials + rewrite OWN logp rows (XCD-local RAW).
template<bool BF16>
__device__ __forceinline__ void pipeline(
    const int* __restrict__ tok, const void* __restrict__ emb,
    const void* __restrict__ hidden,
    const void* __restrict__ attn_w, const void* __restrict__ attn_b,
    const void* __restrict__ enc,
    const void* __restrict__ comb_w, const void* __restrict__ comb_b,
    const void* __restrict__ gwih, const void* __restrict__ gwhh,
    const void* __restrict__ gbih, const void* __restrict__ gbhh,
    const void* __restrict__ out_w, const void* __restrict__ out_b,
    float* __restrict__ ws, void* __restrict__ out)
{
    unsigned* bars = (unsigned*)(ws + WS_BARS);
    const int tid  = threadIdx.x;
    const int lane = tid & 63;
    const int wid  = tid >> 6;
    const int bx   = blockIdx.x;
    const size_t es = BF16 ? 2 : 4;

    __shared__ float lds[256];
    __shared__ float wsm[256];

    if (bx < 64) {
        const int wv = (bx << 2) | wid;   // 0..255
        const int j8 = lane * 8;

        // ---- P0: attn scores = concat(emb, h0) @ attn_w.T + attn_b ----
        {
            float xin[8];
            if (lane < 32) ld8<BF16>(emb, (size_t)tok[0] * H + j8, xin);
            else           ld8<BF16>(hidden, (size_t)(j8 - H), xin);   // hidden[0]
            float wf[8]; ld8<BF16>(attn_w, (size_t)wv * L2H + j8, wf);
            float v = 0.f;
            #pragma unroll
            for (int q = 0; q < 8; ++q) v += xin[q] * wf[q];
            #pragma unroll
            for (int off = 32; off; off >>= 1) v += __shfl_xor(v, off);
            if (lane == 0) stc(ws + WS_SCORE + wv, v + ld1<BF16>(attn_b, wv));
        }
        gbar(bars, 0, true, 4);

        // ---- P1: softmax over 256 scores + apply slices (blocks 0..15) ----
        if (bx < 16) {
            float s = ldc(ws + WS_SCORE + tid);
            lds[tid] = s; __syncthreads();
            for (int off = 128; off; off >>= 1) {
                if (tid < off) lds[tid] = fmaxf(lds[tid], lds[tid + off]);
                __syncthreads();
            }
            float M = lds[0]; __syncthreads();
            float e = __expf(s - M);
            lds[tid] = e; __syncthreads();
            for (int off = 128; off; off >>= 1) {
                if (tid < off) lds[tid] += lds[tid + off];
                __syncthreads();
            }
            float w = e / lds[0];
            wsm[tid] = w; __syncthreads();
            if (bx == 0) st<BF16>(out, OUT_ATTN + tid, w);
            int l0 = bx * 16;
            float acc = 0.f;
            #pragma unroll
            for (int k = 0; k < 16; ++k)
                acc += wsm[l0 + k] * ld1<BF16>(enc, (size_t)(l0 + k) * H + tid);
            atomicAdd(&ws[WS_APP + tid], acc);   // device-scope RMW at LLC
        }
        gbar(bars, 1, true, 4);

        // ---- P2: x = relu(concat(emb, attn_applied) @ comb_w.T + comb_b) ----
        {
            float xin[8];
            if (lane < 32) {
                ld8<BF16>(emb, (size_t)tok[0] * H + j8, xin);
            } else {
                #pragma unroll
                for (int q = 0; q < 8; ++q) xin[q] = ldc(ws + WS_APP + (j8 - H) + q);
            }
            float wf[8]; ld8<BF16>(comb_w, (size_t)wv * L2H + j8, wf);
            float v = 0.f;
            #pragma unroll
            for (int q = 0; q < 8; ++q) v += xin[q] * wf[q];
            #pragma unroll
            for (int off = 32; off; off >>= 1) v += __shfl_xor(v, off);
            if (lane == 0) stc(ws + WS_X0 + wv, fmaxf(v + ld1<BF16>(comb_b, wv), 0.f));
        }
        gbar(bars, 2, true, 4);

        // ---- P3..P6: 4 GRU layers (PyTorch gate order r,z,n), wave per row ----
        const int e4 = lane * 4;
        for (int l = 0; l < NLAYERS; ++l) {
            const float* xin_p = ws + ((l & 1) ? WS_X1 : WS_X0);
            float*       xout  = ws + ((l & 1) ? WS_X0 : WS_X1);
            const char* wih = (const char*)gwih + (size_t)l * 3 * H * H * es;
            const char* whh = (const char*)gwhh + (size_t)l * 3 * H * H * es;
            const char* bih = (const char*)gbih + (size_t)l * 3 * H * es;
            const char* bhh = (const char*)gbhh + (size_t)l * 3 * H * es;
            const char* hprev = (const char*)hidden + (size_t)l * H * es;
            char*       hout  = (char*)out + (size_t)(OUT_HID + l * H) * es;

            float4 xv;
            xv.x = ldc(xin_p + e4);     xv.y = ldc(xin_p + e4 + 1);
            xv.z = ldc(xin_p + e4 + 2); xv.w = ldc(xin_p + e4 + 3);
            float4 hv = ld4<BF16>(hprev, e4);
            const int i = wv;

            float4 wri = ld4<BF16>(wih, (size_t)(i        ) * H + e4);
            float4 wzi = ld4<BF16>(wih, (size_t)(H + i    ) * H + e4);
            float4 wni = ld4<BF16>(wih, (size_t)(2 * H + i) * H + e4);
            float4 wrh = ld4<BF16>(whh, (size_t)(i        ) * H + e4);
            float4 wzh = ld4<BF16>(whh, (size_t)(H + i    ) * H + e4);
            float4 wnh = ld4<BF16>(whh, (size_t)(2 * H + i) * H + e4);

            float a = wri.x * xv.x + wri.y * xv.y + wri.z * xv.z + wri.w * xv.w
                    + wrh.x * hv.x + wrh.y * hv.y + wrh.z * hv.z + wrh.w * hv.w;
            float b = wzi.x * xv.x + wzi.y * xv.y + wzi.z * xv.z + wzi.w * xv.w
                    + wzh.x * hv.x + wzh.y * hv.y + wzh.z * hv.z + wzh.w * hv.w;
            float c = wni.x * xv.x + wni.y * xv.y + wni.z * xv.z + wni.w * xv.w;
            float d = wnh.x * hv.x + wnh.y * hv.y + wnh.z * hv.z + wnh.w * hv.w;

            #pragma unroll
            for (int off = 32; off; off >>= 1) {
                a += __shfl_xor(a, off);
                b += __shfl_xor(b, off);
                c += __shfl_xor(c, off);
                d += __shfl_xor(d, off);
            }
            if (lane == 0) {
                float r = 1.f / (1.f + __expf(-(a + ld1<BF16>(bih, i) + ld1<BF16>(bhh, i))));
                float z = 1.f / (1.f + __expf(-(b + ld1<BF16>(bih, H + i) + ld1<BF16>(bhh, H + i))));
                float n = tanhf(c + ld1<BF16>(bih, 2 * H + i) + r * (d + ld1<BF16>(bhh, 2 * H + i)));
                float hold = ld1<BF16>(hprev, i);
                float hn = (1.f - z) * n + z * hold;
                stc(xout + i, hn);
                st<BF16>(hout, i, hn);
            }
            gbar(bars, 3 + l, true, 4);   // bar 6 doubles as "x ready" for all
        }
    } else {
        gbar(bars, 6, false, 4);          // wait for pre-logits chain
    }

    // ---- P7: logits GEMV + online-softmax partials (all 256 blocks) ----
    // 2048 row-groups of 32 lanes; 8 rows in flight per thread => 8 MB in
    // flight device-wide => HBM-BW-bound. Rows 0..49151 in 3 clean sweeps,
    // then 1105-row tail.
    {
        const int grp = (bx << 3) | (tid >> 5);   // 0..2047
        const int l32 = tid & 31;

        float xf[8];
        #pragma unroll
        for (int q = 0; q < 8; ++q) xf[q] = ldc(ws + WS_X0 + l32 * 8 + q);

        float m = -1e30f, s = 0.f;
        #pragma unroll
        for (int it = 0; it < 3; ++it) {
            const int rb = it * 16384 + grp;
            float wf[8][8], bb[8];
            #pragma unroll
            for (int k = 0; k < 8; ++k) {
                ld8<BF16>(out_w, (size_t)(rb + (k << 11)) * H + l32 * 8, wf[k]);
                bb[k] = ld1<BF16>(out_b, rb + (k << 11));
            }
            #pragma unroll
            for (int k = 0; k < 8; ++k) {
                float v = wf[k][0]*xf[0] + wf[k][1]*xf[1] + wf[k][2]*xf[2] + wf[k][3]*xf[3]
                        + wf[k][4]*xf[4] + wf[k][5]*xf[5] + wf[k][6]*xf[6] + wf[k][7]*xf[7];
                #pragma unroll
                for (int off = 16; off; off >>= 1) v += __shfl_xor(v, off);
                v += bb[k];
                if (l32 == 0) st<BF16>(out, OUT_LOGP + rb + (k << 11), v);
                float mn = fmaxf(m, v);
                s = s * __expf(m - mn) + __expf(v - mn);
                m = mn;
            }
        }
        if (grp < VOCAB - 49152) {   // tail: 1105 rows
            int r = 49152 + grp;
            float wf[8]; ld8<BF16>(out_w, (size_t)r * H + l32 * 8, wf);
            float v = wf[0]*xf[0] + wf[1]*xf[1] + wf[2]*xf[2] + wf[3]*xf[3]
                    + wf[4]*xf[4] + wf[5]*xf[5] + wf[6]*xf[6] + wf[7]*xf[7];
            #pragma unroll
            for (int off = 16; off; off >>= 1) v += __shfl_xor(v, off);
            v += ld1<BF16>(out_b, r);
            if (l32 == 0) st<BF16>(out, OUT_LOGP + r, v);
            float mn = fmaxf(m, v);
            s = s * __expf(m - mn) + __expf(v - mn);
            m = mn;
        }

        // merge the wave's two 32-lane groups, then 4 waves -> block partial
        {
            float mo = __shfl_xor(m, 32), so = __shfl_xor(s, 32);
            float M = fmaxf(m, mo);
            s = s * __expf(m - M) + so * __expf(mo - M);
            m = M;
        }
        if (lane == 0) { lds[wid] = m; lds[4 + wid] = s; }
        __syncthreads();
        if (tid == 0) {
            float M01 = fmaxf(lds[0], lds[1]);
            float S01 = lds[4] * __expf(lds[0] - M01) + lds[5] * __expf(lds[1] - M01);
            float M23 = fmaxf(lds[2], lds[3]);
            float S23 = lds[6] * __expf(lds[2] - M23) + lds[7] * __expf(lds[3] - M23);
            float Mx = fmaxf(M01, M23);
            float S  = S01 * __expf(M01 - Mx) + S23 * __expf(M23 - Mx);
            stc(ws + WS_PM + bx, Mx);
            stc(ws + WS_PS + bx, S);
        }
    }
    gbar(bars, 7, true, 16);

    // ---- P8: combine 256 partials (redundant per block) + rewrite OWN rows ----
    {
        float m = ldc(ws + WS_PM + tid);
        float s = ldc(ws + WS_PS + tid);
        #pragma unroll
        for (int off = 32; off; off >>= 1) {
            float mo = __shfl_xor(m, off), so = __shfl_xor(s, off);
            float M = fmaxf(m, mo);
            s = s * __expf(m - M) + so * __expf(mo - M);
            m = M;
        }
        if (lane == 0) { lds[wid] = m; lds[4 + wid] = s; }
        __syncthreads();
        if (tid == 0) {
            float M01 = fmaxf(lds[0], lds[1]);
            float S01 = lds[4] * __expf(lds[0] - M01) + lds[5] * __expf(lds[1] - M01);
            float M23 = fmaxf(lds[2], lds[3]);
            float S23 = lds[6] * __expf(lds[2] - M23) + lds[7] * __expf(lds[3] - M23);
            float Mx = fmaxf(M01, M23);
            float S  = S01 * __expf(M01 - Mx) + S23 * __expf(M23 - Mx);
            lds[8] = Mx + __logf(S);
        }
        __syncthreads();
        float c = lds[8];
        // rewrite exactly the rows this block's groups produced in P7
        // (read-after-write stays within this block's XCD L2)
        const int grp = (bx << 3) | (tid >> 5);
        const int j   = tid & 31;                       // (base, k) combo
        int r = ((j >> 3) << 14) + ((j & 7) << 11) + grp;
        if (r < VOCAB) {
            float v = ld1<BF16>(out, OUT_LOGP + r);
            st<BF16>(out, OUT_LOGP + r, v - c);
        }
    }
}

__global__ __launch_bounds__(256, 1) void k_all(
    const int* __restrict__ tok, const void* __restrict__ emb,
    const void* __restrict__ hidden,
    const void* __restrict__ attn_w, const void* __restrict__ attn_b,
    const void* __restrict__ enc,
    const void* __restrict__ comb_w, const void* __restrict__ comb_b,
    const void* __restrict__ gwih, const void* __restrict__ gwhh,
    const void* __restrict__ gbih, const void* __restrict__ gbhh,
    const void* __restrict__ out_w, const void* __restrict__ out_b,
    float* __restrict__ ws, void* __restrict__ out)
{
    if (ws[WS_FLAG] > 0.5f)
        pipeline<true >(tok, emb, hidden, attn_w, attn_b, enc, comb_w, comb_b,
                        gwih, gwhh, gbih, gbhh, out_w, out_b, ws, out);
    else
        pipeline<false>(tok, emb, hidden, attn_w, attn_b, enc, comb_w, comb_b,
                        gwih, gwhh, gbih, gbhh, out_w, out_b, ws, out);
}

extern "C" void kernel_launch(void* const* d_in, const int* in_sizes, int n_in,
                              void* d_out, int out_size, void* d_ws, size_t ws_size,
                              hipStream_t stream) {
    const int* tok = (const int*)d_in[0];
    float* ws = (float*)d_ws;

    k_init<<<dim3(1), dim3(256), 0, stream>>>(d_in[3], ws);
    k_all<<<dim3(NBLK), dim3(256), 0, stream>>>(
        tok, d_in[3], d_in[1], d_in[4], d_in[5], d_in[2], d_in[6], d_in[7],
        d_in[8], d_in[9], d_in[10], d_in[11], d_in[12], d_in[13],
        ws, d_out);
}